// Round 1
// baseline (734.108 us; speedup 1.0000x reference)
//
#include <hip/hip_runtime.h>

#define NEG_SLOPE 0.2f

// ---------------- CSR build ----------------

__global__ void k_fill1(int* hist, int N) {
    int i = blockIdx.x * 256 + threadIdx.x;
    if (i < N) hist[i] = 1;  // self-loop pre-counted
}

__global__ void k_count(const int* __restrict__ dst, int* hist, int E) {
    int i = blockIdx.x * 256 + threadIdx.x;
    if (i < E) atomicAdd(&hist[dst[i]], 1);
}

// single-block scan, 8 elements/thread
__global__ void k_scan(const int* __restrict__ hist, int* __restrict__ rowptr, int n) {
    __shared__ int sums[1024];
    __shared__ int carry;
    if (threadIdx.x == 0) carry = 0;
    __syncthreads();
    const int CHUNK = 1024 * 8;
    for (int base = 0; base < n; base += CHUNK) {
        int idx0 = base + threadIdx.x * 8;
        int v[8];
        int tsum = 0;
#pragma unroll
        for (int i = 0; i < 8; ++i) {
            int idx = idx0 + i;
            v[i] = (idx < n) ? hist[idx] : 0;
            tsum += v[i];
        }
        sums[threadIdx.x] = tsum;
        __syncthreads();
        for (int off = 1; off < 1024; off <<= 1) {
            int t = (threadIdx.x >= off) ? sums[threadIdx.x - off] : 0;
            __syncthreads();
            sums[threadIdx.x] += t;
            __syncthreads();
        }
        int excl = carry + sums[threadIdx.x] - tsum;
#pragma unroll
        for (int i = 0; i < 8; ++i) {
            int idx = idx0 + i;
            if (idx < n) rowptr[idx] = excl;
            excl += v[i];
        }
        __syncthreads();
        if (threadIdx.x == 1023) carry += sums[1023];
        __syncthreads();
    }
    if (threadIdx.x == 0) rowptr[n] = carry;
}

__global__ void k_cursor_init(const int* __restrict__ rowptr, int* cursor, int* col, int N) {
    int i = blockIdx.x * 256 + threadIdx.x;
    if (i < N) {
        int p = rowptr[i];
        col[p] = i;          // self-loop in slot 0 of each segment
        cursor[i] = p + 1;
    }
}

__global__ void k_scatter(const int* __restrict__ src, const int* __restrict__ dst,
                          int* cursor, int* col, int E) {
    int i = blockIdx.x * 256 + threadIdx.x;
    if (i < E) {
        int p = atomicAdd(&cursor[dst[i]], 1);
        col[p] = src[i];
    }
}

// ---------------- GEMM1: h1[N,256] = x[N,256] @ W1[256,256] ----------------

__global__ void k_gemm1(const float* __restrict__ x, const float* __restrict__ W,
                        float* __restrict__ h1, int N) {
    __shared__ float As[64][17];   // [m][k], pad to break write conflicts
    __shared__ float Bs[16][64];   // [k][n]
    const int tid = threadIdx.x;
    const int tx = tid & 15;
    const int ty = tid >> 4;
    const int row0 = blockIdx.y * 64;
    const int col0 = blockIdx.x * 64;
    float acc[4][4] = {};
    for (int k0 = 0; k0 < 256; k0 += 16) {
        {
            int kk = tid & 15;
            int mm = tid >> 4;
#pragma unroll
            for (int i = 0; i < 4; ++i) {
                int m = mm + i * 16;
                int row = row0 + m;
                As[m][kk] = (row < N) ? x[row * 256 + k0 + kk] : 0.f;
            }
        }
        {
            int nn = tid & 63;
            int kq = tid >> 6;
#pragma unroll
            for (int i = 0; i < 4; ++i) {
                int k = kq + i * 4;
                Bs[k][nn] = W[(k0 + k) * 256 + col0 + nn];
            }
        }
        __syncthreads();
#pragma unroll
        for (int kk = 0; kk < 16; ++kk) {
            float a[4], b[4];
#pragma unroll
            for (int i = 0; i < 4; ++i) a[i] = As[ty + 16 * i][kk];
#pragma unroll
            for (int j = 0; j < 4; ++j) b[j] = Bs[kk][tx + 16 * j];
#pragma unroll
            for (int i = 0; i < 4; ++i)
#pragma unroll
                for (int j = 0; j < 4; ++j) acc[i][j] += a[i] * b[j];
        }
        __syncthreads();
    }
#pragma unroll
    for (int i = 0; i < 4; ++i) {
        int row = row0 + ty + 16 * i;
        if (row < N) {
#pragma unroll
            for (int j = 0; j < 4; ++j)
                h1[row * 256 + col0 + tx + 16 * j] = acc[i][j];
        }
    }
}

// ---------------- alpha1: per-node per-head dots ----------------

__global__ void k_alpha1(const float* __restrict__ h1, const float* __restrict__ asrc,
                         const float* __restrict__ adst, float* __restrict__ as1,
                         float* __restrict__ ad1, int N) {
    int n = blockIdx.x;
    int tid = threadIdx.x;
    float v = h1[n * 256 + tid];
    float a = v * asrc[tid];
    float d = v * adst[tid];
#pragma unroll
    for (int mq = 1; mq < 64; mq <<= 1) {
        a += __shfl_xor(a, mq);
        d += __shfl_xor(d, mq);
    }
    if ((tid & 63) == 0) {
        int head = tid >> 6;
        as1[n * 4 + head] = a;
        ad1[n * 4 + head] = d;
    }
}

// ---------------- agg1: per-dst online segment softmax + aggregate + bias + ELU ----------------

__global__ void k_agg1(const float* __restrict__ h1, const float* __restrict__ as1,
                       const float* __restrict__ ad1, const int* __restrict__ rowptr,
                       const int* __restrict__ col, const float* __restrict__ b1,
                       float* __restrict__ h2in, int N) {
    int n = blockIdx.x;
    int tid = threadIdx.x;  // head = tid>>6, channel-within-head = tid&63
    int head = tid >> 6;
    int beg = rowptr[n], end = rowptr[n + 1];
    float adv = ad1[n * 4 + head];
    float m = -__builtin_inff(), s = 0.f, acc = 0.f;
    for (int j = beg; j < end; ++j) {
        int src = col[j];
        float e = as1[src * 4 + head] + adv;
        e = (e >= 0.f) ? e : NEG_SLOPE * e;
        float nm = fmaxf(m, e);
        float scale = __expf(m - nm) * (m == -__builtin_inff() ? 0.f : 1.f);
        float p = __expf(e - nm);
        s = s * scale + p;
        acc = acc * scale + p * h1[src * 256 + tid];
        m = nm;
    }
    float v = acc / (s + 1e-16f) + b1[tid];
    h2in[n * 256 + tid] = (v > 0.f) ? v : expm1f(v);
}

// ---------------- GEMM2 + alpha2 epilogue ----------------

__global__ void k_gemm2(const float* __restrict__ h, const float* __restrict__ W2,
                        const float* __restrict__ asrc, const float* __restrict__ adst,
                        float* __restrict__ z, float* __restrict__ as2,
                        float* __restrict__ ad2, int N) {
    __shared__ float Ws[256 * 32];
    __shared__ float Hs[8][256];
    int tid = threadIdx.x;
    for (int i = tid; i < 256 * 32; i += 256) Ws[i] = W2[i];
    int row0 = blockIdx.x * 8;
    for (int i = tid; i < 8 * 256; i += 256) {
        int r = i >> 8, k = i & 255;
        int row = row0 + r;
        Hs[r][k] = (row < N) ? h[row * 256 + k] : 0.f;
    }
    __syncthreads();
    int r = tid >> 5, c = tid & 31;
    float acc = 0.f;
#pragma unroll 8
    for (int k = 0; k < 256; ++k) acc += Hs[r][k] * Ws[k * 32 + c];
    float va = acc * asrc[c];
    float vd = acc * adst[c];
#pragma unroll
    for (int mq = 1; mq < 32; mq <<= 1) {  // masks <32 stay within 32-lane halves
        va += __shfl_xor(va, mq);
        vd += __shfl_xor(vd, mq);
    }
    int row = row0 + r;
    if (row < N) {
        z[row * 32 + c] = acc;
        if (c == 0) {
            as2[row] = va;
            ad2[row] = vd;
        }
    }
}

// ---------------- agg2: per-dst softmax + aggregate + bias, 32 channels ----------------

__global__ void k_agg2(const float* __restrict__ z, const float* __restrict__ as2,
                       const float* __restrict__ ad2, const int* __restrict__ rowptr,
                       const int* __restrict__ col, const float* __restrict__ b2,
                       float* __restrict__ out, int N) {
    int wave = threadIdx.x >> 6;
    int n = blockIdx.x * 4 + wave;
    if (n >= N) return;
    int c = threadIdx.x & 31;  // upper 32 lanes compute redundantly
    int beg = rowptr[n], end = rowptr[n + 1];
    float adv = ad2[n];
    float m = -__builtin_inff(), s = 0.f, acc = 0.f;
    for (int j = beg; j < end; ++j) {
        int src = col[j];
        float e = as2[src] + adv;
        e = (e >= 0.f) ? e : NEG_SLOPE * e;
        float nm = fmaxf(m, e);
        float scale = __expf(m - nm) * (m == -__builtin_inff() ? 0.f : 1.f);
        float p = __expf(e - nm);
        s = s * scale + p;
        acc = acc * scale + p * z[src * 32 + c];
        m = nm;
    }
    if ((threadIdx.x & 63) < 32) out[n * 32 + c] = acc / (s + 1e-16f) + b2[c];
}

// ---------------- launch ----------------

extern "C" void kernel_launch(void* const* d_in, const int* in_sizes, int n_in,
                              void* d_out, int out_size, void* d_ws, size_t ws_size,
                              hipStream_t stream) {
    const float* x    = (const float*)d_in[0];
    const int*   ei   = (const int*)d_in[1];
    const float* W1   = (const float*)d_in[2];
    const float* a_s1 = (const float*)d_in[3];
    const float* a_d1 = (const float*)d_in[4];
    const float* b1   = (const float*)d_in[5];
    const float* W2   = (const float*)d_in[6];
    const float* a_s2 = (const float*)d_in[7];
    const float* a_d2 = (const float*)d_in[8];
    const float* b2   = (const float*)d_in[9];
    float* out = (float*)d_out;

    const int N = in_sizes[0] / 256;
    const int E = in_sizes[1] / 2;
    const int* srcIdx = ei;
    const int* dstIdx = ei + E;

    char* ws = (char*)d_ws;
    size_t off = 0;
    auto alloc = [&](size_t bytes) {
        void* p = ws + off;
        off += (bytes + 255) & ~(size_t)255;
        return p;
    };
    float* h1     = (float*)alloc((size_t)N * 256 * 4);
    float* h2in   = (float*)alloc((size_t)N * 256 * 4);
    float* z      = (float*)alloc((size_t)N * 32 * 4);
    float* as1    = (float*)alloc((size_t)N * 4 * 4);
    float* ad1    = (float*)alloc((size_t)N * 4 * 4);
    float* as2    = (float*)alloc((size_t)N * 4);
    float* ad2    = (float*)alloc((size_t)N * 4);
    int*   hist   = (int*)alloc((size_t)N * 4);
    int*   cursor = (int*)alloc((size_t)N * 4);
    int*   rowptr = (int*)alloc((size_t)(N + 1) * 4);
    int*   col    = (int*)alloc((size_t)(E + N) * 4);

    // CSR build (dst-sorted adjacency, self-loops included)
    k_fill1<<<(N + 255) / 256, 256, 0, stream>>>(hist, N);
    k_count<<<(E + 255) / 256, 256, 0, stream>>>(dstIdx, hist, E);
    k_scan<<<1, 1024, 0, stream>>>(hist, rowptr, N);
    k_cursor_init<<<(N + 255) / 256, 256, 0, stream>>>(rowptr, cursor, col, N);
    k_scatter<<<(E + 255) / 256, 256, 0, stream>>>(srcIdx, dstIdx, cursor, col, E);

    // layer 1
    dim3 g1(256 / 64, (N + 63) / 64);
    k_gemm1<<<g1, 256, 0, stream>>>(x, W1, h1, N);
    k_alpha1<<<N, 256, 0, stream>>>(h1, a_s1, a_d1, as1, ad1, N);
    k_agg1<<<N, 256, 0, stream>>>(h1, as1, ad1, rowptr, col, b1, h2in, N);

    // layer 2
    k_gemm2<<<(N + 7) / 8, 256, 0, stream>>>(h2in, W2, a_s2, a_d2, z, as2, ad2, N);
    k_agg2<<<(N + 3) / 4, 256, 0, stream>>>(z, as2, ad2, rowptr, col, b2, out, N);
}

// Round 2
// 552.315 us; speedup vs baseline: 1.3291x; 1.3291x over previous
//
#include <hip/hip_runtime.h>

#define NEG_SLOPE 0.2f

// ---------------- CSR build ----------------

__global__ void k_fill1(int* hist, int N) {
    int i = blockIdx.x * 256 + threadIdx.x;
    if (i < N) hist[i] = 1;  // self-loop pre-counted
}

__global__ void k_count(const int* __restrict__ dst, int* hist, int E) {
    int i = blockIdx.x * 256 + threadIdx.x;
    if (i < E) atomicAdd(&hist[dst[i]], 1);
}

// single-block scan, 8 elements/thread
__global__ void k_scan(const int* __restrict__ hist, int* __restrict__ rowptr, int n) {
    __shared__ int sums[1024];
    __shared__ int carry;
    if (threadIdx.x == 0) carry = 0;
    __syncthreads();
    const int CHUNK = 1024 * 8;
    for (int base = 0; base < n; base += CHUNK) {
        int idx0 = base + threadIdx.x * 8;
        int v[8];
        int tsum = 0;
#pragma unroll
        for (int i = 0; i < 8; ++i) {
            int idx = idx0 + i;
            v[i] = (idx < n) ? hist[idx] : 0;
            tsum += v[i];
        }
        sums[threadIdx.x] = tsum;
        __syncthreads();
        for (int off = 1; off < 1024; off <<= 1) {
            int t = (threadIdx.x >= off) ? sums[threadIdx.x - off] : 0;
            __syncthreads();
            sums[threadIdx.x] += t;
            __syncthreads();
        }
        int excl = carry + sums[threadIdx.x] - tsum;
#pragma unroll
        for (int i = 0; i < 8; ++i) {
            int idx = idx0 + i;
            if (idx < n) rowptr[idx] = excl;
            excl += v[i];
        }
        __syncthreads();
        if (threadIdx.x == 1023) carry += sums[1023];
        __syncthreads();
    }
    if (threadIdx.x == 0) rowptr[n] = carry;
}

__global__ void k_cursor_init(const int* __restrict__ rowptr, int* cursor, int* col, int N) {
    int i = blockIdx.x * 256 + threadIdx.x;
    if (i < N) {
        int p = rowptr[i];
        col[p] = i;          // self-loop in slot 0 of each segment
        cursor[i] = p + 1;
    }
}

__global__ void k_scatter(const int* __restrict__ src, const int* __restrict__ dst,
                          int* cursor, int* col, int E) {
    int i = blockIdx.x * 256 + threadIdx.x;
    if (i < E) {
        int p = atomicAdd(&cursor[dst[i]], 1);
        col[p] = src[i];
    }
}

// ---------------- GEMM1: h1[N,256] = x[N,256] @ W1[256,256] ----------------
// 128x128 tile, 8x8 per thread, float4 LDS fragments (A staged k-major).

__global__ __launch_bounds__(256, 4) void k_gemm1(const float* __restrict__ x,
                                                  const float* __restrict__ W,
                                                  float* __restrict__ h1, int N) {
    __shared__ float As[16 * 132];  // k-major: As[k][m], stride 132
    __shared__ float Bs[16 * 132];  // k-major: Bs[k][n], stride 132
    const int tid = threadIdx.x;
    const int tx8 = tid & 15;   // col group
    const int ty8 = tid >> 4;   // row group
    const int row0 = blockIdx.y * 128;
    const int col0 = blockIdx.x * 128;
    float acc[8][8] = {};
    for (int k0 = 0; k0 < 256; k0 += 16) {
        // stage A with transpose: 128 rows x 16 k
#pragma unroll
        for (int i = 0; i < 2; ++i) {
            int idx = tid + 256 * i;       // 0..511
            int r = idx >> 2;              // 0..127
            int kc = (idx & 3) * 4;        // 0,4,8,12
            int row = row0 + r;
            float4 v = (row < N) ? *(const float4*)(x + (size_t)row * 256 + k0 + kc)
                                 : make_float4(0.f, 0.f, 0.f, 0.f);
            As[(kc + 0) * 132 + r] = v.x;
            As[(kc + 1) * 132 + r] = v.y;
            As[(kc + 2) * 132 + r] = v.z;
            As[(kc + 3) * 132 + r] = v.w;
        }
        // stage B: 16 k x 128 cols (already k-major in W)
#pragma unroll
        for (int i = 0; i < 2; ++i) {
            int idx = tid + 256 * i;
            int k = idx >> 5;              // 0..15
            int cc = (idx & 31) * 4;       // 0..124
            *(float4*)(Bs + k * 132 + cc) =
                *(const float4*)(W + (size_t)(k0 + k) * 256 + col0 + cc);
        }
        __syncthreads();
#pragma unroll
        for (int kk = 0; kk < 16; ++kk) {
            float4 a0 = *(const float4*)(As + kk * 132 + ty8 * 8);
            float4 a1 = *(const float4*)(As + kk * 132 + ty8 * 8 + 4);
            float4 b0 = *(const float4*)(Bs + kk * 132 + tx8 * 8);
            float4 b1 = *(const float4*)(Bs + kk * 132 + tx8 * 8 + 4);
            float a[8] = {a0.x, a0.y, a0.z, a0.w, a1.x, a1.y, a1.z, a1.w};
            float b[8] = {b0.x, b0.y, b0.z, b0.w, b1.x, b1.y, b1.z, b1.w};
#pragma unroll
            for (int ii = 0; ii < 8; ++ii)
#pragma unroll
                for (int jj = 0; jj < 8; ++jj)
                    acc[ii][jj] = fmaf(a[ii], b[jj], acc[ii][jj]);
        }
        __syncthreads();
    }
#pragma unroll
    for (int ii = 0; ii < 8; ++ii) {
        int row = row0 + ty8 * 8 + ii;
        if (row < N) {
            float4 s0 = make_float4(acc[ii][0], acc[ii][1], acc[ii][2], acc[ii][3]);
            float4 s1 = make_float4(acc[ii][4], acc[ii][5], acc[ii][6], acc[ii][7]);
            *(float4*)(h1 + (size_t)row * 256 + col0 + tx8 * 8) = s0;
            *(float4*)(h1 + (size_t)row * 256 + col0 + tx8 * 8 + 4) = s1;
        }
    }
}

// ---------------- alpha1: per-node per-head dots ----------------

__global__ void k_alpha1(const float* __restrict__ h1, const float* __restrict__ asrc,
                         const float* __restrict__ adst, float* __restrict__ as1,
                         float* __restrict__ ad1, int N) {
    int n = blockIdx.x;
    int tid = threadIdx.x;
    float v = h1[(size_t)n * 256 + tid];
    float a = v * asrc[tid];
    float d = v * adst[tid];
#pragma unroll
    for (int mq = 1; mq < 64; mq <<= 1) {
        a += __shfl_xor(a, mq);
        d += __shfl_xor(d, mq);
    }
    if ((tid & 63) == 0) {
        int head = tid >> 6;
        as1[n * 4 + head] = a;
        ad1[n * 4 + head] = d;
    }
}

// ---------------- edge1: unnormalized softmax weights (all 4 heads) ----------------
// One wave per dst node; lanes parallel over edges. alpha[j] = exp(leaky(e)) (float4),
// inv1[n] = 1/(sum + 1e-16) per head. (Max-shift skipped: |e| is small, exact in ratio.)

__global__ void k_edge1(const float* __restrict__ as1, const float* __restrict__ ad1,
                        const int* __restrict__ rowptr, const int* __restrict__ col,
                        float* __restrict__ alpha, float* __restrict__ inv1, int N) {
    int n = blockIdx.x * 4 + (threadIdx.x >> 6);
    if (n >= N) return;
    int l = threadIdx.x & 63;
    int beg = __builtin_amdgcn_readfirstlane(rowptr[n]);
    int end = __builtin_amdgcn_readfirstlane(rowptr[n + 1]);
    float4 ad = *(const float4*)(ad1 + (size_t)n * 4);
    float4 sum = make_float4(0.f, 0.f, 0.f, 0.f);
    for (int j = beg + l; j < end; j += 64) {
        int src = col[j];
        float4 as = *(const float4*)(as1 + (size_t)src * 4);
        float4 e;
        e.x = as.x + ad.x; e.x = fmaxf(e.x, NEG_SLOPE * e.x);
        e.y = as.y + ad.y; e.y = fmaxf(e.y, NEG_SLOPE * e.y);
        e.z = as.z + ad.z; e.z = fmaxf(e.z, NEG_SLOPE * e.z);
        e.w = as.w + ad.w; e.w = fmaxf(e.w, NEG_SLOPE * e.w);
        float4 p;
        p.x = __expf(e.x); p.y = __expf(e.y); p.z = __expf(e.z); p.w = __expf(e.w);
        *(float4*)(alpha + (size_t)j * 4) = p;
        sum.x += p.x; sum.y += p.y; sum.z += p.z; sum.w += p.w;
    }
#pragma unroll
    for (int mq = 1; mq < 64; mq <<= 1) {
        sum.x += __shfl_xor(sum.x, mq);
        sum.y += __shfl_xor(sum.y, mq);
        sum.z += __shfl_xor(sum.z, mq);
        sum.w += __shfl_xor(sum.w, mq);
    }
    if (l == 0) {
        float4 iv;
        iv.x = 1.f / (sum.x + 1e-16f);
        iv.y = 1.f / (sum.y + 1e-16f);
        iv.z = 1.f / (sum.z + 1e-16f);
        iv.w = 1.f / (sum.w + 1e-16f);
        *(float4*)(inv1 + (size_t)n * 4) = iv;
    }
}

// ---------------- gather1: acc = sum_j p_j * h1[src_j], then *inv + bias + ELU ----------------
// One wave per dst node; lane covers 4 channels (float4). Edge loop is wave-uniform:
// col[j] / alpha[j] become scalar loads.

__global__ void k_gather1(const float* __restrict__ h1, const float* __restrict__ alpha,
                          const float* __restrict__ inv1, const int* __restrict__ rowptr,
                          const int* __restrict__ col, const float* __restrict__ b1,
                          float* __restrict__ h2in, int N) {
    int n = blockIdx.x * 4 + (threadIdx.x >> 6);
    if (n >= N) return;
    int l = threadIdx.x & 63;
    int head = l >> 4;
    int beg = __builtin_amdgcn_readfirstlane(rowptr[n]);
    int end = __builtin_amdgcn_readfirstlane(rowptr[n + 1]);
    float4 acc0 = make_float4(0.f, 0.f, 0.f, 0.f);
    float4 acc1 = make_float4(0.f, 0.f, 0.f, 0.f);
    int j = beg;
    for (; j + 1 < end; j += 2) {
        int s0 = __builtin_amdgcn_readfirstlane(col[j]);
        int s1 = __builtin_amdgcn_readfirstlane(col[j + 1]);
        float4 p40 = *(const float4*)(alpha + (size_t)j * 4);
        float4 p41 = *(const float4*)(alpha + (size_t)(j + 1) * 4);
        float p0 = (head < 2) ? (head == 0 ? p40.x : p40.y) : (head == 2 ? p40.z : p40.w);
        float p1 = (head < 2) ? (head == 0 ? p41.x : p41.y) : (head == 2 ? p41.z : p41.w);
        float4 h0 = *(const float4*)(h1 + (size_t)s0 * 256 + l * 4);
        float4 h1v = *(const float4*)(h1 + (size_t)s1 * 256 + l * 4);
        acc0.x = fmaf(p0, h0.x, acc0.x); acc0.y = fmaf(p0, h0.y, acc0.y);
        acc0.z = fmaf(p0, h0.z, acc0.z); acc0.w = fmaf(p0, h0.w, acc0.w);
        acc1.x = fmaf(p1, h1v.x, acc1.x); acc1.y = fmaf(p1, h1v.y, acc1.y);
        acc1.z = fmaf(p1, h1v.z, acc1.z); acc1.w = fmaf(p1, h1v.w, acc1.w);
    }
    if (j < end) {
        int s0 = __builtin_amdgcn_readfirstlane(col[j]);
        float4 p40 = *(const float4*)(alpha + (size_t)j * 4);
        float p0 = (head < 2) ? (head == 0 ? p40.x : p40.y) : (head == 2 ? p40.z : p40.w);
        float4 h0 = *(const float4*)(h1 + (size_t)s0 * 256 + l * 4);
        acc0.x = fmaf(p0, h0.x, acc0.x); acc0.y = fmaf(p0, h0.y, acc0.y);
        acc0.z = fmaf(p0, h0.z, acc0.z); acc0.w = fmaf(p0, h0.w, acc0.w);
    }
    acc0.x += acc1.x; acc0.y += acc1.y; acc0.z += acc1.z; acc0.w += acc1.w;
    float4 iv4 = *(const float4*)(inv1 + (size_t)n * 4);
    float iv = (head < 2) ? (head == 0 ? iv4.x : iv4.y) : (head == 2 ? iv4.z : iv4.w);
    float4 bb = *(const float4*)(b1 + l * 4);
    float4 v;
    v.x = acc0.x * iv + bb.x;
    v.y = acc0.y * iv + bb.y;
    v.z = acc0.z * iv + bb.z;
    v.w = acc0.w * iv + bb.w;
    v.x = (v.x > 0.f) ? v.x : (__expf(v.x) - 1.f);
    v.y = (v.y > 0.f) ? v.y : (__expf(v.y) - 1.f);
    v.z = (v.z > 0.f) ? v.z : (__expf(v.z) - 1.f);
    v.w = (v.w > 0.f) ? v.w : (__expf(v.w) - 1.f);
    *(float4*)(h2in + (size_t)n * 256 + l * 4) = v;
}

// ---------------- GEMM2: z[N,32] = h2in[N,256] @ W2[256,32], fused alpha2 dots ----------------
// Block: 32 rows. Lane: r = tid>>3 (row in block chunk of 32? r in 0..31), cg = tid&7 (4 cols).

__global__ __launch_bounds__(256) void k_gemm2(const float* __restrict__ h,
                                               const float* __restrict__ W2,
                                               const float* __restrict__ asrc,
                                               const float* __restrict__ adst,
                                               float* __restrict__ z, float* __restrict__ as2,
                                               float* __restrict__ ad2, int N) {
    __shared__ float Ws[256 * 32];      // full W2, k-major (row-major already)
    __shared__ float Hs[32 * 68];       // 32 rows x 64 k chunk, stride 68
    const int tid = threadIdx.x;
    const int r = tid >> 3;             // 0..31 row in block
    const int cg = tid & 7;             // col group (4 cols)
    const int row0 = blockIdx.x * 32;
    const int row = row0 + r;
    for (int i = tid; i < 256 * 32; i += 256) Ws[i] = W2[i];
    float4 acc = make_float4(0.f, 0.f, 0.f, 0.f);
    for (int k0 = 0; k0 < 256; k0 += 64) {
        __syncthreads();
#pragma unroll
        for (int i = 0; i < 2; ++i) {
            int idx = tid + 256 * i;     // 0..511
            int rr = idx >> 4;           // 0..31
            int c4 = (idx & 15) * 4;     // 0..60
            int rw = row0 + rr;
            float4 v = (rw < N) ? *(const float4*)(h + (size_t)rw * 256 + k0 + c4)
                                : make_float4(0.f, 0.f, 0.f, 0.f);
            *(float4*)(Hs + rr * 68 + c4) = v;
        }
        __syncthreads();
#pragma unroll
        for (int k = 0; k < 64; k += 4) {
            float4 hv = *(const float4*)(Hs + r * 68 + k);
            float4 w0 = *(const float4*)(Ws + (k0 + k) * 32 + cg * 4);
            float4 w1 = *(const float4*)(Ws + (k0 + k + 1) * 32 + cg * 4);
            float4 w2 = *(const float4*)(Ws + (k0 + k + 2) * 32 + cg * 4);
            float4 w3 = *(const float4*)(Ws + (k0 + k + 3) * 32 + cg * 4);
            acc.x = fmaf(hv.x, w0.x, acc.x); acc.y = fmaf(hv.x, w0.y, acc.y);
            acc.z = fmaf(hv.x, w0.z, acc.z); acc.w = fmaf(hv.x, w0.w, acc.w);
            acc.x = fmaf(hv.y, w1.x, acc.x); acc.y = fmaf(hv.y, w1.y, acc.y);
            acc.z = fmaf(hv.y, w1.z, acc.z); acc.w = fmaf(hv.y, w1.w, acc.w);
            acc.x = fmaf(hv.z, w2.x, acc.x); acc.y = fmaf(hv.z, w2.y, acc.y);
            acc.z = fmaf(hv.z, w2.z, acc.z); acc.w = fmaf(hv.z, w2.w, acc.w);
            acc.x = fmaf(hv.w, w3.x, acc.x); acc.y = fmaf(hv.w, w3.y, acc.y);
            acc.z = fmaf(hv.w, w3.z, acc.z); acc.w = fmaf(hv.w, w3.w, acc.w);
        }
    }
    // alpha2 dots: va = sum_c z_c * asrc_c, vd likewise
    float4 a4 = *(const float4*)(asrc + cg * 4);
    float4 d4 = *(const float4*)(adst + cg * 4);
    float va = acc.x * a4.x + acc.y * a4.y + acc.z * a4.z + acc.w * a4.w;
    float vd = acc.x * d4.x + acc.y * d4.y + acc.z * d4.z + acc.w * d4.w;
#pragma unroll
    for (int mq = 1; mq < 8; mq <<= 1) {
        va += __shfl_xor(va, mq);
        vd += __shfl_xor(vd, mq);
    }
    if (row < N) {
        *(float4*)(z + (size_t)row * 32 + cg * 4) = acc;
        if (cg == 0) {
            as2[row] = va;
            ad2[row] = vd;
        }
    }
}

// ---------------- edge2: unnormalized softmax weights, 1 head ----------------

__global__ void k_edge2(const float* __restrict__ as2, const float* __restrict__ ad2,
                        const int* __restrict__ rowptr, const int* __restrict__ col,
                        float* __restrict__ alpha2, float* __restrict__ inv2, int N) {
    int n = blockIdx.x * 4 + (threadIdx.x >> 6);
    if (n >= N) return;
    int l = threadIdx.x & 63;
    int beg = __builtin_amdgcn_readfirstlane(rowptr[n]);
    int end = __builtin_amdgcn_readfirstlane(rowptr[n + 1]);
    float adn = ad2[n];
    float sum = 0.f;
    for (int j = beg + l; j < end; j += 64) {
        int src = col[j];
        float e = as2[src] + adn;
        e = fmaxf(e, NEG_SLOPE * e);
        float p = __expf(e);
        alpha2[j] = p;
        sum += p;
    }
#pragma unroll
    for (int mq = 1; mq < 64; mq <<= 1) sum += __shfl_xor(sum, mq);
    if (l == 0) inv2[n] = 1.f / (sum + 1e-16f);
}

// ---------------- gather2: out = (sum_j p_j * z[src_j]) * inv + b2 ----------------
// One wave per node; 8 edges in parallel (lane>>3), 8 channels-groups (lane&7, x4 ch).

__global__ void k_gather2(const float* __restrict__ z, const float* __restrict__ alpha2,
                          const float* __restrict__ inv2, const int* __restrict__ rowptr,
                          const int* __restrict__ col, const float* __restrict__ b2,
                          float* __restrict__ out, int N) {
    int n = blockIdx.x * 4 + (threadIdx.x >> 6);
    if (n >= N) return;
    int l = threadIdx.x & 63;
    int eo = l >> 3;                    // edge offset 0..7
    int cg = l & 7;                     // 4-channel group
    int beg = __builtin_amdgcn_readfirstlane(rowptr[n]);
    int end = __builtin_amdgcn_readfirstlane(rowptr[n + 1]);
    float4 acc = make_float4(0.f, 0.f, 0.f, 0.f);
    for (int j0 = beg; j0 < end; j0 += 8) {
        int idx = j0 + eo;
        bool valid = idx < end;
        int idc = valid ? idx : (end - 1);
        int src = col[idc];
        float p = valid ? alpha2[idc] : 0.f;
        float4 zv = *(const float4*)(z + (size_t)src * 32 + cg * 4);
        acc.x = fmaf(p, zv.x, acc.x); acc.y = fmaf(p, zv.y, acc.y);
        acc.z = fmaf(p, zv.z, acc.z); acc.w = fmaf(p, zv.w, acc.w);
    }
#pragma unroll
    for (int mq = 8; mq < 64; mq <<= 1) {
        acc.x += __shfl_xor(acc.x, mq);
        acc.y += __shfl_xor(acc.y, mq);
        acc.z += __shfl_xor(acc.z, mq);
        acc.w += __shfl_xor(acc.w, mq);
    }
    if (eo == 0) {
        float iv = inv2[n];
        float4 bb = *(const float4*)(b2 + cg * 4);
        float4 v;
        v.x = acc.x * iv + bb.x;
        v.y = acc.y * iv + bb.y;
        v.z = acc.z * iv + bb.z;
        v.w = acc.w * iv + bb.w;
        *(float4*)(out + (size_t)n * 32 + cg * 4) = v;
    }
}

// ---------------- launch ----------------

extern "C" void kernel_launch(void* const* d_in, const int* in_sizes, int n_in,
                              void* d_out, int out_size, void* d_ws, size_t ws_size,
                              hipStream_t stream) {
    const float* x    = (const float*)d_in[0];
    const int*   ei   = (const int*)d_in[1];
    const float* W1   = (const float*)d_in[2];
    const float* a_s1 = (const float*)d_in[3];
    const float* a_d1 = (const float*)d_in[4];
    const float* b1   = (const float*)d_in[5];
    const float* W2   = (const float*)d_in[6];
    const float* a_s2 = (const float*)d_in[7];
    const float* a_d2 = (const float*)d_in[8];
    const float* b2   = (const float*)d_in[9];
    float* out = (float*)d_out;

    const int N = in_sizes[0] / 256;
    const int E = in_sizes[1] / 2;
    const int EP = E + N;  // with self-loops
    const int* srcIdx = ei;
    const int* dstIdx = ei + E;

    char* ws = (char*)d_ws;
    size_t off = 0;
    auto alloc = [&](size_t bytes) {
        void* p = ws + off;
        off += (bytes + 255) & ~(size_t)255;
        return p;
    };
    float* h1     = (float*)alloc((size_t)N * 256 * 4);   // reused as z after gather1
    float* h2in   = (float*)alloc((size_t)N * 256 * 4);
    float* alpha  = (float*)alloc((size_t)EP * 16);       // layer1 float4/edge; reused as alpha2
    float* as1    = (float*)alloc((size_t)N * 16);        // reused as as2
    float* ad1    = (float*)alloc((size_t)N * 16);        // reused as ad2
    float* inv1   = (float*)alloc((size_t)N * 16);        // reused as inv2
    int*   hist   = (int*)alloc((size_t)N * 4);
    int*   cursor = (int*)alloc((size_t)N * 4);
    int*   rowptr = (int*)alloc((size_t)(N + 1) * 4);
    int*   col    = (int*)alloc((size_t)EP * 4);

    float* z      = h1;
    float* alpha2 = alpha;
    float* as2    = as1;
    float* ad2    = ad1;
    float* inv2   = inv1;

    // CSR build (dst-sorted adjacency, self-loops included)
    k_fill1<<<(N + 255) / 256, 256, 0, stream>>>(hist, N);
    k_count<<<(E + 255) / 256, 256, 0, stream>>>(dstIdx, hist, E);
    k_scan<<<1, 1024, 0, stream>>>(hist, rowptr, N);
    k_cursor_init<<<(N + 255) / 256, 256, 0, stream>>>(rowptr, cursor, col, N);
    k_scatter<<<(E + 255) / 256, 256, 0, stream>>>(srcIdx, dstIdx, cursor, col, E);

    // layer 1
    dim3 g1(2, (N + 127) / 128);
    k_gemm1<<<g1, 256, 0, stream>>>(x, W1, h1, N);
    k_alpha1<<<N, 256, 0, stream>>>(h1, a_s1, a_d1, as1, ad1, N);
    k_edge1<<<(N + 3) / 4, 256, 0, stream>>>(as1, ad1, rowptr, col, alpha, inv1, N);
    k_gather1<<<(N + 3) / 4, 256, 0, stream>>>(h1, alpha, inv1, rowptr, col, b1, h2in, N);

    // layer 2
    k_gemm2<<<(N + 31) / 32, 256, 0, stream>>>(h2in, W2, a_s2, a_d2, z, as2, ad2, N);
    k_edge2<<<(N + 3) / 4, 256, 0, stream>>>(as2, ad2, rowptr, col, alpha2, inv2, N);
    k_gather2<<<(N + 3) / 4, 256, 0, stream>>>(z, alpha2, inv2, rowptr, col, b2, out, N);
}